// Round 8
// baseline (112.594 us; speedup 1.0000x reference)
//
#include <hip/hip_runtime.h>
#include <math.h>

// Chamfer loss, B=4, C=3, Np=Ng=8192, fp32 — MFMA single-pass formulation.
// d2 = p^2 + g^2 - 2 p.g packed into the 16 used K-slots of ONE
// v_mfma_f32_16x16x32_bf16 per 16x16 tile, with hi/lo bf16 splitting for
// fp32-grade accuracy (all cross products kept; residual ~3e-5 in d2):
//   A = [-2phx,-2phy,-2phz, -2phx,-2phy,-2phz, -2plx,-2ply,-2plz,
//        p2h, p2l, 1, 1, -2plx,-2ply,-2plz]
//   B = [ghx,ghy,ghz, glx,gly,glz, ghx,ghy,ghz, 1, 1, g2h, g2l, glx,gly,glz]
// acc = full d2. Row-fold -> predict-side mins, col-fold -> gt-side mins:
// single pass produces both directions. Fragment layouts (verified m89/m118):
//   A[m=lane&15][k=quad*8+j], B[k=quad*8+j][n=lane&15],
//   D[row=quad*4+reg][col=lane&15].  Quads 2,3 (k=16..31) read a 16-B zero
// scratch in LDS (address select, no masking). Combine: LDS atomicMin
// (uint bits of clamped d2), then global atomicMin; R6 poison-ticket finish
// (0xAA ws poison = +inf for uint-min and ticket base; no init dispatch).

#define B_        4
#define N_        8192
#define THREADS   256
#define ROWS_PB   256                 // rows per block = 4 waves * 4 rt * 16
#define ROWBLKS   (N_ / ROWS_PB)      // 32
#define MRANGE    1024                // gt points per block
#define MSPLIT    (N_ / MRANGE)       // 8
#define MTILES    (MRANGE / 16)       // 64
#define NGROUPS   B_
#define BLKS_PER_GROUP (ROWBLKS * MSPLIT)   // 256
#define POISON    0xAAAAAAAAu
#define INF_BITS  0x7F800000u

typedef __bf16 bf16x8 __attribute__((ext_vector_type(8)));
typedef float  f32x4  __attribute__((ext_vector_type(4)));

// smem pool layout (bytes), all 16-aligned:
//   [0,16)            zero scratch (reads for quads 2,3)
//   [16, 8208)        As: 256 rows * 32 B (16 bf16 slots)
//   [8208, 40976)     Bs: 1024 pts * 32 B
//   [40976, 45072)    colmin: 1024 * u32
//   [45072, 46096)    rowmin: 256 * u32
#define SM_ZERO   0
#define SM_A      16
#define SM_B      8208
#define SM_COL    40976
#define SM_ROW    45072
#define SM_BYTES  46096

__device__ __forceinline__ unsigned short bf16_rne(float f) {
    unsigned u = __float_as_uint(f);
    return (unsigned short)((u + 0x7FFFu + ((u >> 16) & 1u)) >> 16);
}
__device__ __forceinline__ float bf16_tof(unsigned short h) {
    return __uint_as_float(((unsigned)h) << 16);
}

// A-side (predict) 16 slots
__device__ __forceinline__ void slotsA(const float* base, int n, unsigned short* dst) {
    float x = base[n], y = base[N_ + n], z = base[2 * N_ + n];
    float p2 = fmaf(x, x, fmaf(y, y, z * z));
    unsigned short hx = bf16_rne(x), hy = bf16_rne(y), hz = bf16_rne(z);
    float lxf = x - bf16_tof(hx), lyf = y - bf16_tof(hy), lzf = z - bf16_tof(hz);
    unsigned short mhx = bf16_rne(-2.0f * bf16_tof(hx));   // exact
    unsigned short mhy = bf16_rne(-2.0f * bf16_tof(hy));
    unsigned short mhz = bf16_rne(-2.0f * bf16_tof(hz));
    unsigned short mlx = bf16_rne(-2.0f * bf16_tof(bf16_rne(lxf)));
    unsigned short mly = bf16_rne(-2.0f * bf16_tof(bf16_rne(lyf)));
    unsigned short mlz = bf16_rne(-2.0f * bf16_tof(bf16_rne(lzf)));
    unsigned short p2h = bf16_rne(p2);
    unsigned short p2l = bf16_rne(p2 - bf16_tof(p2h));
    const unsigned short ONE = 0x3F80;
    dst[0] = mhx;  dst[1] = mhy;  dst[2] = mhz;
    dst[3] = mhx;  dst[4] = mhy;  dst[5] = mhz;
    dst[6] = mlx;  dst[7] = mly;  dst[8] = mlz;
    dst[9] = p2h;  dst[10] = p2l; dst[11] = ONE; dst[12] = ONE;
    dst[13] = mlx; dst[14] = mly; dst[15] = mlz;
}

// B-side (gt) 16 slots
__device__ __forceinline__ void slotsB(const float* base, int m, unsigned short* dst) {
    float x = base[m], y = base[N_ + m], z = base[2 * N_ + m];
    float g2 = fmaf(x, x, fmaf(y, y, z * z));
    unsigned short hx = bf16_rne(x), hy = bf16_rne(y), hz = bf16_rne(z);
    unsigned short lx = bf16_rne(x - bf16_tof(hx));
    unsigned short ly = bf16_rne(y - bf16_tof(hy));
    unsigned short lz = bf16_rne(z - bf16_tof(hz));
    unsigned short g2h = bf16_rne(g2);
    unsigned short g2l = bf16_rne(g2 - bf16_tof(g2h));
    const unsigned short ONE = 0x3F80;
    dst[0] = hx;  dst[1] = hy;  dst[2] = hz;
    dst[3] = lx;  dst[4] = ly;  dst[5] = lz;
    dst[6] = hx;  dst[7] = hy;  dst[8] = hz;
    dst[9] = ONE; dst[10] = ONE; dst[11] = g2h; dst[12] = g2l;
    dst[13] = lx; dst[14] = ly; dst[15] = lz;
}

// ws (32-bit words):
//   [0, 32768)      predict-side mins [b][n]  (uint bits; poison = +inf)
//   [32768, 65536)  gt-side mins      [b][m]
//   [65536, 65540)  gcnt[4]  (per-batch tickets, poison base)
//   [65600]         fcnt
//   [65664, 65668)  gsum[4]

__global__ __launch_bounds__(THREADS, 3)
void chamfer_mfma_kernel(const float* __restrict__ P, const float* __restrict__ G,
                         unsigned* __restrict__ mins, unsigned* __restrict__ gcnt,
                         unsigned* __restrict__ fcnt, float* __restrict__ gsum,
                         float* __restrict__ out)
{
    __shared__ __align__(16) char smem[SM_BYTES];
    __shared__ float red[THREADS];
    __shared__ unsigned s_ticket;

    const int t      = threadIdx.x;
    const int rowblk = blockIdx.x;     // 0..31
    const int mspl   = blockIdx.y;     // 0..7
    const int b      = blockIdx.z;     // 0..3
    const int rowbase = rowblk * ROWS_PB;
    const int mbase   = mspl * MRANGE;

    const float* Pb = P + (size_t)b * 3 * N_;
    const float* Gb = G + (size_t)b * 3 * N_;

    // ---- stage: zero scratch, min arrays, A-slots (1 row/thread), B-slots (4/thread)
    if (t < 4) ((unsigned*)(smem + SM_ZERO))[t] = 0u;
    unsigned* colmin = (unsigned*)(smem + SM_COL);
    unsigned* rowmin = (unsigned*)(smem + SM_ROW);
#pragma unroll
    for (int k = 0; k < 4; ++k) colmin[k * THREADS + t] = INF_BITS;
    rowmin[t] = INF_BITS;

    slotsA(Pb, rowbase + t, (unsigned short*)(smem + SM_A) + t * 16);
#pragma unroll
    for (int k = 0; k < 4; ++k)
        slotsB(Gb, mbase + k * THREADS + t,
               (unsigned short*)(smem + SM_B) + (k * THREADS + t) * 16);
    __syncthreads();

    // ---- per-wave fragment setup ----
    const int wave = t >> 6, lane = t & 63, quad = lane >> 4, col = lane & 15;

    bf16x8 afrag[4];
#pragma unroll
    for (int rt = 0; rt < 4; ++rt) {
        const int rowl = wave * 64 + rt * 16 + col;
        const char* ap = (quad < 2) ? (smem + SM_A + rowl * 32 + quad * 16)
                                    : (smem + SM_ZERO);
        afrag[rt] = *(const bf16x8*)ap;
    }
    const char* bp = (quad < 2) ? (smem + SM_B + col * 32 + quad * 16)
                                : (smem + SM_ZERO);
    const int binc = (quad < 2) ? 16 * 32 : 0;   // bytes per m-tile

    float rmin[4][4];
#pragma unroll
    for (int rt = 0; rt < 4; ++rt)
#pragma unroll
        for (int r = 0; r < 4; ++r) rmin[rt][r] = 3.4e38f;

    // ---- main sweep: 64 m-tiles, 4 row-tiles each ----
    for (int mt = 0; mt < MTILES; ++mt) {
        bf16x8 bfrag = *(const bf16x8*)bp;
        bp += binc;
        float cp = 3.4e38f;
#pragma unroll
        for (int rt = 0; rt < 4; ++rt) {
            f32x4 z = {0.0f, 0.0f, 0.0f, 0.0f};
            f32x4 acc = __builtin_amdgcn_mfma_f32_16x16x32_bf16(afrag[rt], bfrag, z, 0, 0, 0);
            rmin[rt][0] = fminf(rmin[rt][0], acc[0]);
            rmin[rt][1] = fminf(rmin[rt][1], acc[1]);
            rmin[rt][2] = fminf(rmin[rt][2], acc[2]);
            rmin[rt][3] = fminf(rmin[rt][3], acc[3]);
            cp = fminf(cp, fminf(fminf(acc[0], acc[1]), fminf(acc[2], acc[3])));
        }
        atomicMin(&colmin[mt * 16 + col], __float_as_uint(fmaxf(cp, 1e-12f)));
    }

    // ---- row-side fold into LDS (16 cols collapse per address) ----
#pragma unroll
    for (int rt = 0; rt < 4; ++rt)
#pragma unroll
        for (int r = 0; r < 4; ++r)
            atomicMin(&rowmin[wave * 64 + rt * 16 + quad * 4 + r],
                      __float_as_uint(fmaxf(rmin[rt][r], 1e-12f)));
    __syncthreads();

    // ---- global flush ----
    atomicMin(&mins[(size_t)b * N_ + rowbase + t], rowmin[t]);
#pragma unroll
    for (int k = 0; k < 4; ++k) {
        const int i = k * THREADS + t;
        atomicMin(&mins[32768 + (size_t)b * N_ + mbase + i], colmin[i]);
    }

    // ---- per-batch ticket: last of 256 blocks finalizes batch b ----
    __syncthreads();
    if (t == 0) {
        __threadfence();
        s_ticket = atomicAdd(&gcnt[b], 1u);
    }
    __syncthreads();
    if (s_ticket != POISON + (unsigned)(BLKS_PER_GROUP - 1)) return;

    // ---- batch leader: sqrt-sum both sides (16384 mins) ----
    __threadfence();
    const uint4* v0 = (const uint4*)(mins + (size_t)b * N_);
    const uint4* v1 = (const uint4*)(mins + 32768 + (size_t)b * N_);
    float acc = 0.0f;
#pragma unroll
    for (int k = 0; k < N_ / 4 / THREADS; ++k) {   // 8
        uint4 q = v0[k * THREADS + t];
        uint4 w = v1[k * THREADS + t];
        acc += sqrtf(__uint_as_float(q.x)) + sqrtf(__uint_as_float(q.y))
             + sqrtf(__uint_as_float(q.z)) + sqrtf(__uint_as_float(q.w))
             + sqrtf(__uint_as_float(w.x)) + sqrtf(__uint_as_float(w.y))
             + sqrtf(__uint_as_float(w.z)) + sqrtf(__uint_as_float(w.w));
    }
    red[t] = acc;
    __syncthreads();
    for (int off = 128; off > 0; off >>= 1) {
        if (t < off) red[t] += red[t + off];
        __syncthreads();
    }
    if (t == 0) {
        gsum[b] = red[0];
        __threadfence();
        s_ticket = atomicAdd(fcnt, 1u);
    }
    __syncthreads();
    if (s_ticket != POISON + (unsigned)(NGROUPS - 1)) return;

    __threadfence();
    if (t == 0)
        out[0] = (gsum[0] + gsum[1] + gsum[2] + gsum[3]) * (1.0f / 65536.0f);
}

extern "C" void kernel_launch(void* const* d_in, const int* in_sizes, int n_in,
                              void* d_out, int out_size, void* d_ws, size_t ws_size,
                              hipStream_t stream)
{
    const float* P = (const float*)d_in[0];   // predict_pc [4,3,8192]
    const float* G = (const float*)d_in[1];   // gt_pc      [4,3,8192]
    float* out = (float*)d_out;               // scalar

    unsigned* w    = (unsigned*)d_ws;
    unsigned* mins = w;                       // 65536 words
    unsigned* gcnt = w + 65536;               // 4 words
    unsigned* fcnt = w + 65600;               // 1 word
    float*    gsum = (float*)(w + 65664);     // 4 words

    dim3 grid(ROWBLKS, MSPLIT, B_);           // (32, 8, 4) = 1024 blocks
    chamfer_mfma_kernel<<<grid, THREADS, 0, stream>>>(P, G, mins, gcnt, fcnt, gsum, out);
}